// Round 14
// baseline (487.108 us; speedup 1.0000x reference)
//
#include <hip/hip_runtime.h>
#include <hip/hip_bf16.h>
#include <stdint.h>

#define BB 8
#define LL 4096
#define DD 64
#define KT 64
#define NT (LL / KT)         // 64 tiles
#define QBLK 32
#define MP 72                // bytes per Mt row

typedef short bf16x8 __attribute__((ext_vector_type(8)));
typedef short bf16x4 __attribute__((ext_vector_type(4)));
typedef short bf16x2 __attribute__((ext_vector_type(2)));
typedef float f32x4 __attribute__((ext_vector_type(4)));

#define QSCALE 0.1803368801111204f   // (1/8)*log2(e)

__device__ inline short f2bfs(float x) {
    __hip_bfloat16 h = __float2bfloat16(x);
    return __builtin_bit_cast(short, h);
}

__device__ inline int swzK(int r) { return (r & 3) | (((r >> 3) & 1) << 2); }
__device__ inline int swzV(int r) { return (r & 7) ^ ((r >> 3) & 7); }

// Raw barrier: flush own LDS ops, leave global loads in flight.
__device__ inline void wg_barrier() {
    asm volatile("s_waitcnt lgkmcnt(0)" ::: "memory");
    __builtin_amdgcn_s_barrier();
    __builtin_amdgcn_sched_barrier(0);
}

__global__ void detect_mask_kernel(const uint32_t* __restrict__ w, uint32_t* __restrict__ flag) {
    __shared__ int nonbin;
    if (threadIdx.x == 0) nonbin = 0;
    __syncthreads();
    int bad = 0;
    for (int i = threadIdx.x; i < 4096; i += 256) bad |= (w[i] > 1u) ? 1 : 0;
    if (bad) atomicOr(&nonbin, 1);
    __syncthreads();
    if (threadIdx.x == 0) *flag = (uint32_t)(nonbin != 0);
}

// Block = 32 q-rows, 256 threads / 4 waves (rg=w&1 q-group of 16, ch=w>>1 k-half
// of 64). Grid 1024 -> 4 independent blocks/CU. All mask traffic staged through
// LDS with full-line loads; K/V loads full-line; attn stored direct from regs
// (write-merge proven). Permuted-K QK keeps P in registers for pass-1 PV.
__global__ __launch_bounds__(256, 4) void fused_attn_kernel(
    const float* __restrict__ qg, const float* __restrict__ kg,
    const float* __restrict__ vg, const void* __restrict__ maskv,
    const uint32_t* __restrict__ flagp,
    float* __restrict__ attn, float* __restrict__ outp)
{
    __shared__ alignas(16) ushort Kt[2][KT * 64];     // bf16 K [krow][d] swizzled (16 KB)
    __shared__ alignas(16) ushort Vt[2][64 * KT];     // bf16 V^T [d][k] swizzled (16 KB)
    __shared__ alignas(16) uint8_t Mt[2][QBLK * MP];  // mask tile (4.6 KB)
    __shared__ float Rs[2][QBLK];

    const int tid = (int)threadIdx.x;
    const int w   = tid >> 6, l = tid & 63;
    const int lr  = l & 15, lg = l >> 4;
    const int rg  = w & 1, ch = w >> 1;
    const int id  = (int)blockIdx.x;     // id = qt*8 + b -> batch b stays on XCD b
    const int b   = id & 7;
    const int q0  = (id >> 3) * QBLK;
    const bool mbyte = (*flagp != 0);

    const float* kb = kg + (size_t)b * LL * DD;
    const float* vb = vg + (size_t)b * LL * DD;
    const uint8_t* mb8 = (const uint8_t*)maskv + (size_t)b * LL * LL;
    const int qrow = q0 + 16 * rg + lr;
    const int* mrow32 = (const int*)maskv + (size_t)b * LL * LL + (size_t)qrow * LL + ch * 32 + lg * 8;
    float* arow = attn + (size_t)b * LL * LL + (size_t)qrow * LL + ch * 32 + lg * 8;

    bf16x8 qf0, qf1;
    {
        const float* qp = qg + (size_t)(b * LL + qrow) * DD + lg * 8;
        f32x4 a0 = *(const f32x4*)(qp)      * QSCALE, a1 = *(const f32x4*)(qp + 4)  * QSCALE;
        f32x4 a2 = *(const f32x4*)(qp + 32) * QSCALE, a3 = *(const f32x4*)(qp + 36) * QSCALE;
        #pragma unroll
        for (int e = 0; e < 4; ++e) { qf0[e] = f2bfs(a0[e]); qf0[4 + e] = f2bfs(a1[e]); }
        #pragma unroll
        for (int e = 0; e < 4; ++e) { qf1[e] = f2bfs(a2[e]); qf1[4 + e] = f2bfs(a3[e]); }
    }

    // ---------- staging: every load is full-line coalesced ----------
    const int sr = tid >> 4, sc = tid & 15;   // K/V: 16 rows x 256B per instr
    const int mr = tid >> 3, mc = tid & 7;    // mask: 32 rows x 64B per instr pair
    f32x4 kS[4], vS[4];
    uint64_t mS = 0;

    auto issK = [&](int kt) {
        #pragma unroll
        for (int it = 0; it < 4; ++it)
            kS[it] = *(const f32x4*)(kb + (size_t)(kt * KT + sr + 16 * it) * DD + sc * 4);
    };
    auto issV = [&](int kt) {
        #pragma unroll
        for (int it = 0; it < 4; ++it) {
            const int r = 2 * sr + (it & 1) + 32 * (it >> 1);
            vS[it] = *(const f32x4*)(vb + (size_t)(kt * KT + r) * DD + sc * 4);
        }
    };
    auto issM = [&](int kt) {
        if (mbyte) mS = *(const uint64_t*)(mb8 + (size_t)(q0 + mr) * LL + kt * KT + mc * 8);
    };
    auto comK = [&](int buf) {
        #pragma unroll
        for (int it = 0; it < 4; ++it) {
            const int row = sr + 16 * it;
            bf16x4 t;
            #pragma unroll
            for (int e = 0; e < 4; ++e) t[e] = f2bfs(kS[it][e]);
            *(bf16x4*)&Kt[buf][row * 64 + (((sc >> 1) ^ swzK(row)) << 3) + (sc & 1) * 4] = t;
        }
    };
    auto comV = [&](int buf) {
        #pragma unroll
        for (int p = 0; p < 2; ++p) {
            const int k0 = 2 * sr + 32 * p;
            #pragma unroll
            for (int e = 0; e < 4; ++e) {
                const int d = sc * 4 + e;
                bf16x2 t;
                t[0] = f2bfs(vS[2 * p][e]);
                t[1] = f2bfs(vS[2 * p + 1][e]);
                *(bf16x2*)&Vt[buf][d * 64 + (((k0 >> 3) ^ swzV(d)) << 3) + (k0 & 7)] = t;
            }
        }
    };
    auto comM = [&](int buf) {
        if (mbyte) *(uint64_t*)&Mt[buf][mr * MP + mc * 8] = mS;
    };

    // ================= pass 1: rowsums + unnormalized PV (P in regs) =================
    float rsum = 0.f;
    f32x4 oacc[4];
    #pragma unroll
    for (int g = 0; g < 4; ++g) { f32x4 z = {0.f, 0.f, 0.f, 0.f}; oacc[g] = z; }

    auto body1 = [&](int cur, int kt) {
        uint64_t mu = 0;
        int4 mi0 = {0,0,0,0}, mi1 = {0,0,0,0};
        if (mbyte) mu = *(const uint64_t*)&Mt[cur][(16 * rg + lr) * MP + ch * 32 + lg * 8];
        else { mi0 = *(const int4*)(mrow32 + kt * KT); mi1 = *(const int4*)(mrow32 + kt * KT + 4); }
        float p8[8];
        #pragma unroll
        for (int n = 0; n < 2; ++n) {
            const int krow = ch * 32 + ((lr >> 2) << 3) + (n << 2) + (lr & 3);
            bf16x8 k0 = *(const bf16x8*)&Kt[cur][krow * 64 + ((lg       ^ swzK(krow)) << 3)];
            bf16x8 k1 = *(const bf16x8*)&Kt[cur][krow * 64 + (((4 + lg) ^ swzK(krow)) << 3)];
            f32x4 c = {0.f, 0.f, 0.f, 0.f};
            c = __builtin_amdgcn_mfma_f32_16x16x32_bf16(k0, qf0, c, 0, 0, 0);
            c = __builtin_amdgcn_mfma_f32_16x16x32_bf16(k1, qf1, c, 0, 0, 0);
            #pragma unroll
            for (int j = 0; j < 4; ++j) {
                const int t = n * 4 + j;
                int mk;
                if (mbyte) mk = (int)((mu >> (8 * t)) & 0xffu);
                else {
                    const int4 mi = n ? mi1 : mi0;
                    mk = (j == 0) ? mi.x : (j == 1) ? mi.y : (j == 2) ? mi.z : mi.w;
                }
                const float pv = mk ? 0.f : exp2f(c[j]);
                rsum += pv;
                p8[t] = pv;
            }
        }
        bf16x8 pa;
        #pragma unroll
        for (int t = 0; t < 8; ++t) pa[t] = f2bfs(p8[t]);
        #pragma unroll
        for (int g = 0; g < 4; ++g) {
            const int d = g * 16 + lr;
            bf16x8 vf = *(const bf16x8*)&Vt[cur][d * 64 + (((ch * 4 + lg) ^ swzV(d)) << 3)];
            oacc[g] = __builtin_amdgcn_mfma_f32_16x16x32_bf16(pa, vf, oacc[g], 0, 0, 0);
        }
    };

    issK(0); issV(0); issM(0);
    comK(0); comV(0); comM(0);
    wg_barrier();
    #pragma unroll 1
    for (int kt = 0; kt < NT; ++kt) {
        const int cur = kt & 1;
        const bool more = (kt < NT - 1);
        if (more) { issK(kt + 1); issV(kt + 1); issM(kt + 1); }
        body1(cur, kt);
        if (more) { comK(cur ^ 1); comV(cur ^ 1); comM(cur ^ 1); }
        wg_barrier();
    }

    rsum += __shfl_xor(rsum, 16, 64);
    rsum += __shfl_xor(rsum, 32, 64);
    if (lg == 0) Rs[ch][16 * rg + lr] = rsum;
    __syncthreads();
    const float rinv = 1.0f / (Rs[0][16 * rg + lr] + Rs[1][16 * rg + lr]);

    // epilogue: combine ch-halves of O via retired Kt region, scale, write
    float* OutL = (float*)Kt;   // 32 rows x 68 f32 = 8.7 KB
    if (ch == 1) {
        #pragma unroll
        for (int g = 0; g < 4; ++g)
            #pragma unroll
            for (int j = 0; j < 4; ++j)
                OutL[(16 * rg + lg * 4 + j) * 68 + g * 16 + lr] = oacc[g][j];
    }
    __syncthreads();
    if (ch == 0) {
        #pragma unroll
        for (int j = 0; j < 4; ++j) {
            const int ql = 16 * rg + lg * 4 + j;
            const float ri = 1.0f / (Rs[0][ql] + Rs[1][ql]);
            const size_t orow = (size_t)(b * LL + q0 + ql) * DD;
            #pragma unroll
            for (int g = 0; g < 4; ++g)
                outp[orow + g * 16 + lr] = (oacc[g][j] + OutL[ql * 68 + g * 16 + lr]) * ri;
        }
    }
    __syncthreads();   // OutL reads done before pass-2 restages Kt

    // ================= pass 2: recompute + attn write (direct from regs) =================
    auto body2 = [&](int cur, int kt) {
        uint64_t mu = 0;
        int4 mi0 = {0,0,0,0}, mi1 = {0,0,0,0};
        if (mbyte) mu = *(const uint64_t*)&Mt[cur][(16 * rg + lr) * MP + ch * 32 + lg * 8];
        else { mi0 = *(const int4*)(mrow32 + kt * KT); mi1 = *(const int4*)(mrow32 + kt * KT + 4); }
        #pragma unroll
        for (int n = 0; n < 2; ++n) {
            const int krow = ch * 32 + ((lr >> 2) << 3) + (n << 2) + (lr & 3);
            bf16x8 k0 = *(const bf16x8*)&Kt[cur][krow * 64 + ((lg       ^ swzK(krow)) << 3)];
            bf16x8 k1 = *(const bf16x8*)&Kt[cur][krow * 64 + (((4 + lg) ^ swzK(krow)) << 3)];
            f32x4 c = {0.f, 0.f, 0.f, 0.f};
            c = __builtin_amdgcn_mfma_f32_16x16x32_bf16(k0, qf0, c, 0, 0, 0);
            c = __builtin_amdgcn_mfma_f32_16x16x32_bf16(k1, qf1, c, 0, 0, 0);
            f32x4 pv;
            #pragma unroll
            for (int j = 0; j < 4; ++j) {
                const int t = n * 4 + j;
                int mk;
                if (mbyte) mk = (int)((mu >> (8 * t)) & 0xffu);
                else {
                    const int4 mi = n ? mi1 : mi0;
                    mk = (j == 0) ? mi.x : (j == 1) ? mi.y : (j == 2) ? mi.z : mi.w;
                }
                pv[j] = mk ? 0.f : exp2f(c[j]) * rinv;
            }
            *(f32x4*)(arow + kt * KT + n * 4) = pv;
        }
    };

    issK(0); issM(0);
    comK(0); comM(0);
    wg_barrier();
    #pragma unroll 1
    for (int kt = 0; kt < NT; ++kt) {
        const int cur = kt & 1;
        const bool more = (kt < NT - 1);
        if (more) { issK(kt + 1); issM(kt + 1); }
        body2(cur, kt);
        if (more) { comK(cur ^ 1); comM(cur ^ 1); }
        wg_barrier();
    }
}

extern "C" void kernel_launch(void* const* d_in, const int* in_sizes, int n_in,
                              void* d_out, int out_size, void* d_ws, size_t ws_size,
                              hipStream_t stream) {
    const float* q = (const float*)d_in[0];
    const float* k = (const float*)d_in[1];
    const float* v = (const float*)d_in[2];
    const void* mask = d_in[3];
    float* attn = (float*)d_out;
    float* outp = attn + (size_t)BB * LL * LL;
    uint32_t* flagp = (uint32_t*)d_ws;

    detect_mask_kernel<<<1, 256, 0, stream>>>((const uint32_t*)mask, flagp);
    fused_attn_kernel<<<dim3((LL / QBLK) * BB), 256, 0, stream>>>(q, k, v, mask, flagp, attn, outp);
}

// Round 15
// 368.103 us; speedup vs baseline: 1.3233x; 1.3233x over previous
//
#include <hip/hip_runtime.h>
#include <hip/hip_bf16.h>
#include <stdint.h>

#define BB 8
#define LL 4096
#define DD 64
#define KT 64                // pass-1 k-tile
#define NT (LL / KT)         // 64
#define NP2 (LL / 128)       // 32 pass-2 tiles (128 wide)

typedef short bf16x8 __attribute__((ext_vector_type(8)));
typedef short bf16x2 __attribute__((ext_vector_type(2)));
typedef float f32x4 __attribute__((ext_vector_type(4)));

#define QSCALE 0.1803368801111204f   // (1/8)*log2(e): folds scale + exp->exp2

__device__ inline short f2bfs(float x) {
    __hip_bfloat16 h = __float2bfloat16(x);
    return __builtin_bit_cast(short, h);
}

__device__ inline bf16x8 pack8v(f32x4 a, f32x4 b) {
    bf16x8 r;
    r[0] = f2bfs(a[0]); r[1] = f2bfs(a[1]); r[2] = f2bfs(a[2]); r[3] = f2bfs(a[3]);
    r[4] = f2bfs(b[0]); r[5] = f2bfs(b[1]); r[6] = f2bfs(b[2]); r[7] = f2bfs(b[3]);
    return r;
}

__device__ inline int swzK(int r) { return (r & 3) | (((r >> 3) & 1) << 2); }
__device__ inline int swzV(int r) { return (r & 7) ^ ((r >> 3) & 7); }

// Raw barrier: flush own LDS ops, leave global loads in flight.
__device__ inline void wg_barrier() {
    asm volatile("s_waitcnt lgkmcnt(0)" ::: "memory");
    __builtin_amdgcn_s_barrier();
    __builtin_amdgcn_sched_barrier(0);
}

__global__ void detect_mask_kernel(const uint32_t* __restrict__ w, uint32_t* __restrict__ flag) {
    __shared__ int nonbin;
    if (threadIdx.x == 0) nonbin = 0;
    __syncthreads();
    int bad = 0;
    for (int i = threadIdx.x; i < 4096; i += 256) bad |= (w[i] > 1u) ? 1 : 0;
    if (bad) atomicOr(&nonbin, 1);
    __syncthreads();
    if (threadIdx.x == 0) *flag = (uint32_t)(nonbin != 0);
}

// R11 structure with the prefetch made compiler-proof: 1-deep single-set staging
// (fits the 128-VGPR cap) + sched_barrier(0) pinning load issue BEFORE the body,
// so commit at the bottom waits only on loads issued a full body earlier.
__global__ __launch_bounds__(512, 4) void fused_attn_kernel(
    const float* __restrict__ qg, const float* __restrict__ kg,
    const float* __restrict__ vg, const void* __restrict__ maskv,
    const uint32_t* __restrict__ flagp,
    float* __restrict__ attn, float* __restrict__ outp)
{
    __shared__ alignas(16) ushort KB[4][KT * 64];  // p1: K dbuf {0,1}, V^T dbuf {2,3}; p2: two 128-row K pairs
    __shared__ uint8_t Msk[8][NT][64];             // mask bits [wave][tile][lane] (32 KB)
    __shared__ float Rs[128];                      // exp row sums [ch][q]

    const int tid = (int)threadIdx.x;
    const int w   = tid >> 6, l = tid & 63;
    const int lr  = l & 15, lg = l >> 4;
    const int rg  = w & 3, ch = w >> 2;
    const int id  = (int)blockIdx.x;     // id = qt*8 + b
    const int b   = id & 7;
    const int q0  = (id >> 3) * 64;
    const bool mbyte = (*flagp != 0);

    const float* kb = kg + (size_t)b * LL * DD;
    const float* vb = vg + (size_t)b * LL * DD;

    const int qrow = q0 + 16 * rg + lr;
    const uint8_t* mrow8  = (const uint8_t*)maskv + (size_t)b * LL * LL + (size_t)qrow * LL + ch * 32 + lg * 8;
    const int*     mrow32 = (const int*)maskv     + (size_t)b * LL * LL + (size_t)qrow * LL + ch * 32 + lg * 8;
    float* arow = attn + (size_t)b * LL * LL + (size_t)qrow * LL + ch * 32 + lg * 8;

    bf16x8 qf0, qf1;
    {
        const float* qp = qg + (size_t)(b * LL + qrow) * DD + lg * 8;
        qf0 = pack8v(*(const f32x4*)(qp)      * QSCALE, *(const f32x4*)(qp + 4)  * QSCALE);
        qf1 = pack8v(*(const f32x4*)(qp + 32) * QSCALE, *(const f32x4*)(qp + 36) * QSCALE);
    }

    const int krow0 = tid >> 3, kc8 = tid & 7;
    const int vk2 = tid >> 4, vd4 = tid & 15;

    // ---------- 1-deep staging set (18 VGPRs) ----------
    f32x4 kS0, kS1, vS0, vS1; uint64_t mS = 0;
    auto issS = [&](int kt) {
        const int kbase = kt * KT;
        const float* p = kb + (size_t)(kbase + krow0) * DD + kc8 * 8;
        kS0 = *(const f32x4*)p; kS1 = *(const f32x4*)(p + 4);
        const float* pv = vb + (size_t)(kbase + vk2 * 2) * DD + vd4 * 4;
        vS0 = *(const f32x4*)pv; vS1 = *(const f32x4*)(pv + DD);
        if (mbyte) mS = *(const uint64_t*)(mrow8 + kbase);
    };
    auto comS = [&](int buf) {
        *(bf16x8*)&KB[buf][krow0 * 64 + ((kc8 ^ swzK(krow0)) << 3)] = pack8v(kS0, kS1);
        const int k0 = vk2 * 2;
        #pragma unroll
        for (int e = 0; e < 4; ++e) {
            const int d = vd4 * 4 + e;
            bf16x2 t; t[0] = f2bfs(vS0[e]); t[1] = f2bfs(vS1[e]);
            *(bf16x2*)&KB[2 + buf][d * 64 + (((k0 >> 3) ^ swzV(d)) << 3) + (k0 & 7)] = t;
        }
    };

    // ================= pass 1: sums + unnormalized PV =================
    float rsum = 0.f;
    f32x4 oacc[4];
    #pragma unroll
    for (int g = 0; g < 4; ++g) { f32x4 z = {0.f, 0.f, 0.f, 0.f}; oacc[g] = z; }

    auto p1body = [&](int buf, uint64_t mu, int kt) {
        const int kbase = kt * KT;
        int4 mi0 = {0,0,0,0}, mi1 = {0,0,0,0};
        if (!mbyte) { mi0 = *(const int4*)(mrow32 + kbase); mi1 = *(const int4*)(mrow32 + kbase + 4); }
        uint32_t mbits = 0;
        float p8[8];
        #pragma unroll
        for (int n = 0; n < 2; ++n) {
            const int krow = ch * 32 + ((lr >> 2) << 3) + (n << 2) + (lr & 3);
            bf16x8 k0 = *(const bf16x8*)&KB[buf][krow * 64 + ((lg       ^ swzK(krow)) << 3)];
            bf16x8 k1 = *(const bf16x8*)&KB[buf][krow * 64 + (((4 + lg) ^ swzK(krow)) << 3)];
            f32x4 c = {0.f, 0.f, 0.f, 0.f};
            c = __builtin_amdgcn_mfma_f32_16x16x32_bf16(k0, qf0, c, 0, 0, 0);
            c = __builtin_amdgcn_mfma_f32_16x16x32_bf16(k1, qf1, c, 0, 0, 0);
            #pragma unroll
            for (int j = 0; j < 4; ++j) {
                const int t = n * 4 + j;
                int mk;
                if (mbyte) mk = (int)((mu >> (8 * t)) & 0xffu);
                else {
                    const int4 mi = n ? mi1 : mi0;
                    mk = (j == 0) ? mi.x : (j == 1) ? mi.y : (j == 2) ? mi.z : mi.w;
                }
                mbits |= (mk ? 1u : 0u) << t;
                const float pv = mk ? 0.f : exp2f(c[j]);
                rsum += pv;
                p8[t] = pv;
            }
        }
        Msk[w][kt][l] = (uint8_t)mbits;
        bf16x8 pa;
        #pragma unroll
        for (int t = 0; t < 8; ++t) pa[t] = f2bfs(p8[t]);
        __builtin_amdgcn_s_setprio(1);
        #pragma unroll
        for (int g = 0; g < 4; ++g) {
            const int d = g * 16 + lr;
            bf16x8 vf = *(const bf16x8*)&KB[2 + buf][d * 64 + (((ch * 4 + lg) ^ swzV(d)) << 3)];
            oacc[g] = __builtin_amdgcn_mfma_f32_16x16x32_bf16(pa, vf, oacc[g], 0, 0, 0);
        }
        __builtin_amdgcn_s_setprio(0);
    };

    issS(0);
    __builtin_amdgcn_sched_barrier(0);
    comS(0);
    wg_barrier();
    #pragma unroll 1
    for (int kt = 0; kt < NT; ++kt) {
        const int cur = kt & 1;
        const bool more = (kt < NT - 1);
        const uint64_t mu = mS;          // this tile's mask (loaded last iteration)
        if (more) issS(kt + 1);          // issue next tile's loads...
        __builtin_amdgcn_sched_barrier(0);   // ...and PIN them here (no sinking)
        p1body(cur, mu, kt);
        if (more) comS(cur ^ 1);         // waits (counted) only on the pinned loads
        wg_barrier();
    }

    rsum += __shfl_xor(rsum, 16, 64);
    rsum += __shfl_xor(rsum, 32, 64);
    if (lg == 0) Rs[ch * 64 + 16 * rg + lr] = rsum;
    __syncthreads();
    const float rinv = 1.0f / (Rs[16 * rg + lr] + Rs[64 + 16 * rg + lr]);

    // epilogue: combine ch halves of O via retired KB region (race-fenced)
    float* OutL = (float*)KB;
    if (ch == 1) {
        #pragma unroll
        for (int g = 0; g < 4; ++g)
            #pragma unroll
            for (int j = 0; j < 4; ++j)
                OutL[rg * 1088 + (lg * 4 + j) * 68 + g * 16 + lr] = oacc[g][j];
    }
    __syncthreads();
    if (ch == 0) {
        #pragma unroll
        for (int j = 0; j < 4; ++j) {
            const int ql = 16 * rg + lg * 4 + j;
            const float ri = 1.0f / (Rs[ql] + Rs[64 + ql]);
            const size_t orow = (size_t)(b * LL + q0 + ql) * DD;
            #pragma unroll
            for (int g = 0; g < 4; ++g)
                outp[orow + g * 16 + lr] = (oacc[g][j] + OutL[rg * 1088 + (lg * 4 + j) * 68 + g * 16 + lr]) * ri;
        }
    }
    __syncthreads();   // OutL reads complete BEFORE pass-2 restages KB (fixes R11 race)

    // ================= pass 2: streaming attn write (128-wide tiles) =================
    f32x4 k2[4];
    auto iss2 = [&](int kt2) {
        #pragma unroll
        for (int m = 0; m < 2; ++m) {
            const float* p = kb + (size_t)(kt2 * 128 + krow0 + 64 * m) * DD + kc8 * 8;
            k2[2 * m]     = *(const f32x4*)p;
            k2[2 * m + 1] = *(const f32x4*)(p + 4);
        }
    };
    auto com2 = [&](int pair) {
        #pragma unroll
        for (int m = 0; m < 2; ++m)
            *(bf16x8*)&KB[2 * pair + m][krow0 * 64 + ((kc8 ^ swzK(krow0)) << 3)] = pack8v(k2[2 * m], k2[2 * m + 1]);
    };
    auto p2body = [&](int pair, int idx) {
        const int kbase2 = idx * 128;
        #pragma unroll
        for (int h = 0; h < 2; ++h) {
            const int mb2 = (int)Msk[w][2 * idx + h][l];
            const ushort* Kbuf = KB[2 * pair + h];
            #pragma unroll
            for (int n = 0; n < 2; ++n) {
                const int krow = ch * 32 + ((lr >> 2) << 3) + (n << 2) + (lr & 3);
                bf16x8 k0 = *(const bf16x8*)&Kbuf[krow * 64 + ((lg       ^ swzK(krow)) << 3)];
                bf16x8 k1 = *(const bf16x8*)&Kbuf[krow * 64 + (((4 + lg) ^ swzK(krow)) << 3)];
                f32x4 c = {0.f, 0.f, 0.f, 0.f};
                c = __builtin_amdgcn_mfma_f32_16x16x32_bf16(k0, qf0, c, 0, 0, 0);
                c = __builtin_amdgcn_mfma_f32_16x16x32_bf16(k1, qf1, c, 0, 0, 0);
                f32x4 pv;
                #pragma unroll
                for (int j = 0; j < 4; ++j)
                    pv[j] = ((mb2 >> (n * 4 + j)) & 1) ? 0.f : exp2f(c[j]) * rinv;
                *(f32x4*)(arow + kbase2 + h * 64 + n * 4) = pv;
            }
        }
    };

    iss2(0);
    __builtin_amdgcn_sched_barrier(0);
    com2(0);
    wg_barrier();
    #pragma unroll 1
    for (int kt2 = 0; kt2 < NP2; ++kt2) {
        const int pair = kt2 & 1;
        const bool more = (kt2 < NP2 - 1);
        if (more) iss2(kt2 + 1);
        __builtin_amdgcn_sched_barrier(0);
        p2body(pair, kt2);
        if (more) com2(pair ^ 1);
        wg_barrier();
    }
}

extern "C" void kernel_launch(void* const* d_in, const int* in_sizes, int n_in,
                              void* d_out, int out_size, void* d_ws, size_t ws_size,
                              hipStream_t stream) {
    const float* q = (const float*)d_in[0];
    const float* k = (const float*)d_in[1];
    const float* v = (const float*)d_in[2];
    const void* mask = d_in[3];
    float* attn = (float*)d_out;
    float* outp = attn + (size_t)BB * LL * LL;
    uint32_t* flagp = (uint32_t*)d_ws;

    detect_mask_kernel<<<1, 256, 0, stream>>>((const uint32_t*)mask, flagp);
    fused_attn_kernel<<<dim3((LL / 64) * BB), 512, 0, stream>>>(q, k, v, mask, flagp, attn, outp);
}

// Round 16
// 362.667 us; speedup vs baseline: 1.3431x; 1.0150x over previous
//
#include <hip/hip_runtime.h>
#include <hip/hip_bf16.h>
#include <stdint.h>

#define BB 8
#define LL 4096
#define DD 64
#define KT 64                // pass-1 k-tile
#define NT (LL / KT)         // 64
#define NP2 (LL / 128)       // 32 pass-2 tiles (128 wide)

typedef short bf16x8 __attribute__((ext_vector_type(8)));
typedef short bf16x2 __attribute__((ext_vector_type(2)));
typedef float f32x4 __attribute__((ext_vector_type(4)));

#define QSCALE 0.1803368801111204f   // (1/8)*log2(e): folds scale + exp->exp2

__device__ inline short f2bfs(float x) {
    __hip_bfloat16 h = __float2bfloat16(x);
    return __builtin_bit_cast(short, h);
}

__device__ inline bf16x8 pack8v(f32x4 a, f32x4 b) {
    bf16x8 r;
    r[0] = f2bfs(a[0]); r[1] = f2bfs(a[1]); r[2] = f2bfs(a[2]); r[3] = f2bfs(a[3]);
    r[4] = f2bfs(b[0]); r[5] = f2bfs(b[1]); r[6] = f2bfs(b[2]); r[7] = f2bfs(b[3]);
    return r;
}

__device__ inline int swzK(int r) { return (r & 3) | (((r >> 3) & 1) << 2); }
__device__ inline int swzV(int r) { return (r & 7) ^ ((r >> 3) & 7); }

// Raw barrier: flush own LDS ops, leave global loads in flight.
__device__ inline void wg_barrier() {
    asm volatile("s_waitcnt lgkmcnt(0)" ::: "memory");
    __builtin_amdgcn_s_barrier();
    __builtin_amdgcn_sched_barrier(0);
}

__global__ void detect_mask_kernel(const uint32_t* __restrict__ w, uint32_t* __restrict__ flag) {
    __shared__ int nonbin;
    if (threadIdx.x == 0) nonbin = 0;
    __syncthreads();
    int bad = 0;
    for (int i = threadIdx.x; i < 4096; i += 256) bad |= (w[i] > 1u) ? 1 : 0;
    if (bad) atomicOr(&nonbin, 1);
    __syncthreads();
    if (threadIdx.x == 0) *flag = (uint32_t)(nonbin != 0);
}

// R15 + compiler-proof pipeline: ALL staging issues/commits are UNCONDITIONAL
// (wrapped tile indices) so issue and body share one basic block and the
// machine-sink pass cannot merge the loads down to their use. Pass 1 runs a
// 2-deep A/B register pipeline (issue kt+2 at kt); pass 2 is 1-deep.
__global__ __launch_bounds__(512, 4) void fused_attn_kernel(
    const float* __restrict__ qg, const float* __restrict__ kg,
    const float* __restrict__ vg, const void* __restrict__ maskv,
    const uint32_t* __restrict__ flagp,
    float* __restrict__ attn, float* __restrict__ outp)
{
    __shared__ alignas(16) ushort KB[4][KT * 64];  // p1: K dbuf {0,1}, V^T dbuf {2,3}; p2: two 128-row K pairs
    __shared__ uint8_t Msk[8][NT][64];             // mask bits [wave][tile][lane] (32 KB)
    __shared__ float Rs[128];                      // exp row sums [ch][q]

    const int tid = (int)threadIdx.x;
    const int w   = tid >> 6, l = tid & 63;
    const int lr  = l & 15, lg = l >> 4;
    const int rg  = w & 3, ch = w >> 2;
    const int id  = (int)blockIdx.x;     // id = qt*8 + b
    const int b   = id & 7;
    const int q0  = (id >> 3) * 64;
    const bool mbyte = (*flagp != 0);

    const float* kb = kg + (size_t)b * LL * DD;
    const float* vb = vg + (size_t)b * LL * DD;

    const int qrow = q0 + 16 * rg + lr;
    const uint8_t* mrow8  = (const uint8_t*)maskv + (size_t)b * LL * LL + (size_t)qrow * LL + ch * 32 + lg * 8;
    const int*     mrow32 = (const int*)maskv     + (size_t)b * LL * LL + (size_t)qrow * LL + ch * 32 + lg * 8;
    float* arow = attn + (size_t)b * LL * LL + (size_t)qrow * LL + ch * 32 + lg * 8;

    bf16x8 qf0, qf1;
    {
        const float* qp = qg + (size_t)(b * LL + qrow) * DD + lg * 8;
        qf0 = pack8v(*(const f32x4*)(qp)      * QSCALE, *(const f32x4*)(qp + 4)  * QSCALE);
        qf1 = pack8v(*(const f32x4*)(qp + 32) * QSCALE, *(const f32x4*)(qp + 36) * QSCALE);
    }

    const int krow0 = tid >> 3, kc8 = tid & 7;
    const int vk2 = tid >> 4, vd4 = tid & 15;

    // ---------- 2-deep staging sets (18 VGPRs each) ----------
    f32x4 kA0, kA1, vA0, vA1; uint64_t mA = 0;
    f32x4 kB0, kB1, vB0, vB1; uint64_t mB = 0;
    auto issA = [&](int kt) {
        const int kbase = kt * KT;
        const float* p = kb + (size_t)(kbase + krow0) * DD + kc8 * 8;
        kA0 = *(const f32x4*)p; kA1 = *(const f32x4*)(p + 4);
        const float* pv = vb + (size_t)(kbase + vk2 * 2) * DD + vd4 * 4;
        vA0 = *(const f32x4*)pv; vA1 = *(const f32x4*)(pv + DD);
        if (mbyte) mA = *(const uint64_t*)(mrow8 + kbase);
    };
    auto issB = [&](int kt) {
        const int kbase = kt * KT;
        const float* p = kb + (size_t)(kbase + krow0) * DD + kc8 * 8;
        kB0 = *(const f32x4*)p; kB1 = *(const f32x4*)(p + 4);
        const float* pv = vb + (size_t)(kbase + vk2 * 2) * DD + vd4 * 4;
        vB0 = *(const f32x4*)pv; vB1 = *(const f32x4*)(pv + DD);
        if (mbyte) mB = *(const uint64_t*)(mrow8 + kbase);
    };
    auto comA = [&](int buf) {
        *(bf16x8*)&KB[buf][krow0 * 64 + ((kc8 ^ swzK(krow0)) << 3)] = pack8v(kA0, kA1);
        const int k0 = vk2 * 2;
        #pragma unroll
        for (int e = 0; e < 4; ++e) {
            const int d = vd4 * 4 + e;
            bf16x2 t; t[0] = f2bfs(vA0[e]); t[1] = f2bfs(vA1[e]);
            *(bf16x2*)&KB[2 + buf][d * 64 + (((k0 >> 3) ^ swzV(d)) << 3) + (k0 & 7)] = t;
        }
    };
    auto comB = [&](int buf) {
        *(bf16x8*)&KB[buf][krow0 * 64 + ((kc8 ^ swzK(krow0)) << 3)] = pack8v(kB0, kB1);
        const int k0 = vk2 * 2;
        #pragma unroll
        for (int e = 0; e < 4; ++e) {
            const int d = vd4 * 4 + e;
            bf16x2 t; t[0] = f2bfs(vB0[e]); t[1] = f2bfs(vB1[e]);
            *(bf16x2*)&KB[2 + buf][d * 64 + (((k0 >> 3) ^ swzV(d)) << 3) + (k0 & 7)] = t;
        }
    };

    // ================= pass 1: sums + unnormalized PV =================
    float rsum = 0.f;
    f32x4 oacc[4];
    #pragma unroll
    for (int g = 0; g < 4; ++g) { f32x4 z = {0.f, 0.f, 0.f, 0.f}; oacc[g] = z; }

    auto p1body = [&](int buf, uint64_t mu, int kt) {
        const int kbase = kt * KT;
        int4 mi0 = {0,0,0,0}, mi1 = {0,0,0,0};
        if (!mbyte) { mi0 = *(const int4*)(mrow32 + kbase); mi1 = *(const int4*)(mrow32 + kbase + 4); }
        uint32_t mbits = 0;
        float p8[8];
        #pragma unroll
        for (int n = 0; n < 2; ++n) {
            const int krow = ch * 32 + ((lr >> 2) << 3) + (n << 2) + (lr & 3);
            bf16x8 k0 = *(const bf16x8*)&KB[buf][krow * 64 + ((lg       ^ swzK(krow)) << 3)];
            bf16x8 k1 = *(const bf16x8*)&KB[buf][krow * 64 + (((4 + lg) ^ swzK(krow)) << 3)];
            f32x4 c = {0.f, 0.f, 0.f, 0.f};
            c = __builtin_amdgcn_mfma_f32_16x16x32_bf16(k0, qf0, c, 0, 0, 0);
            c = __builtin_amdgcn_mfma_f32_16x16x32_bf16(k1, qf1, c, 0, 0, 0);
            #pragma unroll
            for (int j = 0; j < 4; ++j) {
                const int t = n * 4 + j;
                int mk;
                if (mbyte) mk = (int)((mu >> (8 * t)) & 0xffu);
                else {
                    const int4 mi = n ? mi1 : mi0;
                    mk = (j == 0) ? mi.x : (j == 1) ? mi.y : (j == 2) ? mi.z : mi.w;
                }
                mbits |= (mk ? 1u : 0u) << t;
                const float pv = mk ? 0.f : exp2f(c[j]);
                rsum += pv;
                p8[t] = pv;
            }
        }
        Msk[w][kt][l] = (uint8_t)mbits;
        bf16x8 pa;
        #pragma unroll
        for (int t = 0; t < 8; ++t) pa[t] = f2bfs(p8[t]);
        __builtin_amdgcn_s_setprio(1);
        #pragma unroll
        for (int g = 0; g < 4; ++g) {
            const int d = g * 16 + lr;
            bf16x8 vf = *(const bf16x8*)&KB[2 + buf][d * 64 + (((ch * 4 + lg) ^ swzV(d)) << 3)];
            oacc[g] = __builtin_amdgcn_mfma_f32_16x16x32_bf16(pa, vf, oacc[g], 0, 0, 0);
        }
        __builtin_amdgcn_s_setprio(0);
    };

    issA(0); issB(1);
    __builtin_amdgcn_sched_barrier(0);
    comA(0);
    wg_barrier();
    #pragma unroll 1
    for (int kt = 0; kt < NT; kt += 2) {
        {   // even: body(buf0, tile kt); A freed -> reissue tile kt+2; commit B (tile kt+1)
            const uint64_t mu = mA;
            issA((kt + 2) & (NT - 1));              // unconditional, wrapped
            __builtin_amdgcn_sched_barrier(0);      // pinned: same basic block as body
            p1body(0, mu, kt);
            comB(1);
            wg_barrier();
        }
        {   // odd: body(buf1, tile kt+1); B freed -> reissue tile kt+3; commit A (tile kt+2)
            const uint64_t mu = mB;
            issB((kt + 3) & (NT - 1));
            __builtin_amdgcn_sched_barrier(0);
            p1body(1, mu, kt + 1);
            comA(0);                                 // final wrapped commit never read
            wg_barrier();
        }
    }

    rsum += __shfl_xor(rsum, 16, 64);
    rsum += __shfl_xor(rsum, 32, 64);
    if (lg == 0) Rs[ch * 64 + 16 * rg + lr] = rsum;
    __syncthreads();
    const float rinv = 1.0f / (Rs[16 * rg + lr] + Rs[64 + 16 * rg + lr]);

    // epilogue: combine ch halves of O via retired KB region (race-fenced)
    float* OutL = (float*)KB;
    if (ch == 1) {
        #pragma unroll
        for (int g = 0; g < 4; ++g)
            #pragma unroll
            for (int j = 0; j < 4; ++j)
                OutL[rg * 1088 + (lg * 4 + j) * 68 + g * 16 + lr] = oacc[g][j];
    }
    __syncthreads();
    if (ch == 0) {
        #pragma unroll
        for (int j = 0; j < 4; ++j) {
            const int ql = 16 * rg + lg * 4 + j;
            const float ri = 1.0f / (Rs[ql] + Rs[64 + ql]);
            const size_t orow = (size_t)(b * LL + q0 + ql) * DD;
            #pragma unroll
            for (int g = 0; g < 4; ++g)
                outp[orow + g * 16 + lr] = (oacc[g][j] + OutL[rg * 1088 + (lg * 4 + j) * 68 + g * 16 + lr]) * ri;
        }
    }
    __syncthreads();   // OutL reads complete BEFORE pass-2 restages KB

    // ================= pass 2: streaming attn write (128-wide tiles, 1-deep) =================
    f32x4 k2[4];
    auto iss2 = [&](int kt2) {
        #pragma unroll
        for (int m = 0; m < 2; ++m) {
            const float* p = kb + (size_t)(kt2 * 128 + krow0 + 64 * m) * DD + kc8 * 8;
            k2[2 * m]     = *(const f32x4*)p;
            k2[2 * m + 1] = *(const f32x4*)(p + 4);
        }
    };
    auto com2 = [&](int pair) {
        #pragma unroll
        for (int m = 0; m < 2; ++m)
            *(bf16x8*)&KB[2 * pair + m][krow0 * 64 + ((kc8 ^ swzK(krow0)) << 3)] = pack8v(k2[2 * m], k2[2 * m + 1]);
    };
    auto p2body = [&](int pair, int idx) {
        const int kbase2 = idx * 128;
        #pragma unroll
        for (int h = 0; h < 2; ++h) {
            const int mb2 = (int)Msk[w][2 * idx + h][l];
            const ushort* Kbuf = KB[2 * pair + h];
            #pragma unroll
            for (int n = 0; n < 2; ++n) {
                const int krow = ch * 32 + ((lr >> 2) << 3) + (n << 2) + (lr & 3);
                bf16x8 k0 = *(const bf16x8*)&Kbuf[krow * 64 + ((lg       ^ swzK(krow)) << 3)];
                bf16x8 k1 = *(const bf16x8*)&Kbuf[krow * 64 + (((4 + lg) ^ swzK(krow)) << 3)];
                f32x4 c = {0.f, 0.f, 0.f, 0.f};
                c = __builtin_amdgcn_mfma_f32_16x16x32_bf16(k0, qf0, c, 0, 0, 0);
                c = __builtin_amdgcn_mfma_f32_16x16x32_bf16(k1, qf1, c, 0, 0, 0);
                f32x4 pv;
                #pragma unroll
                for (int j = 0; j < 4; ++j)
                    pv[j] = ((mb2 >> (n * 4 + j)) & 1) ? 0.f : exp2f(c[j]) * rinv;
                *(f32x4*)(arow + kbase2 + h * 64 + n * 4) = pv;
            }
        }
    };

    iss2(0);
    __builtin_amdgcn_sched_barrier(0);
    com2(0);
    wg_barrier();
    #pragma unroll 1
    for (int kt2 = 0; kt2 < NP2; ++kt2) {
        const int pair = kt2 & 1;
        iss2((kt2 + 1) & (NP2 - 1));                 // unconditional, wrapped
        __builtin_amdgcn_sched_barrier(0);
        p2body(pair, kt2);
        com2(pair ^ 1);                              // final wrapped commit never read
        wg_barrier();
    }
}

extern "C" void kernel_launch(void* const* d_in, const int* in_sizes, int n_in,
                              void* d_out, int out_size, void* d_ws, size_t ws_size,
                              hipStream_t stream) {
    const float* q = (const float*)d_in[0];
    const float* k = (const float*)d_in[1];
    const float* v = (const float*)d_in[2];
    const void* mask = d_in[3];
    float* attn = (float*)d_out;
    float* outp = attn + (size_t)BB * LL * LL;
    uint32_t* flagp = (uint32_t*)d_ws;

    detect_mask_kernel<<<1, 256, 0, stream>>>((const uint32_t*)mask, flagp);
    fused_attn_kernel<<<dim3((LL / 64) * BB), 512, 0, stream>>>(q, k, v, mask, flagp, attn, outp);
}

// Round 17
// 352.620 us; speedup vs baseline: 1.3814x; 1.0285x over previous
//
#include <hip/hip_runtime.h>
#include <hip/hip_bf16.h>
#include <stdint.h>

#define BB 8
#define LL 4096
#define DD 64
#define KT 64
#define NT (LL / KT)         // 64 pass-1 tiles
#define NP2 (LL / 128)       // 32 pass-2 tiles (128 wide)

typedef short bf16x8 __attribute__((ext_vector_type(8)));
typedef float f32x4 __attribute__((ext_vector_type(4)));

#define QSCALE 0.1803368801111204f   // (1/8)*log2(e): folds scale + exp->exp2

__device__ inline short f2bfs(float x) {
    __hip_bfloat16 h = __float2bfloat16(x);
    return __builtin_bit_cast(short, h);
}

__device__ inline bf16x8 pack8v(f32x4 a, f32x4 b) {
    bf16x8 r;
    r[0] = f2bfs(a[0]); r[1] = f2bfs(a[1]); r[2] = f2bfs(a[2]); r[3] = f2bfs(a[3]);
    r[4] = f2bfs(b[0]); r[5] = f2bfs(b[1]); r[6] = f2bfs(b[2]); r[7] = f2bfs(b[3]);
    return r;
}

__device__ inline int swzK(int r) { return (r & 3) | (((r >> 3) & 1) << 2); }
__device__ inline int swzV(int r) { return (r & 7) ^ ((r >> 3) & 7); }

// Raw barrier: flush own LDS ops, leave global/DMA loads in flight.
__device__ inline void wg_barrier() {
    asm volatile("s_waitcnt lgkmcnt(0)" ::: "memory");
    __builtin_amdgcn_s_barrier();
    __builtin_amdgcn_sched_barrier(0);
}

// Direct global->LDS DMA, 16B per lane. LDS dest must be wave-uniform base + lane*16.
__device__ inline void gl_lds16(const ushort* g, ushort* l) {
    __builtin_amdgcn_global_load_lds((const __attribute__((address_space(1))) void*)g,
                                     (__attribute__((address_space(3))) void*)l, 16, 0, 0);
}

__global__ void detect_mask_kernel(const uint32_t* __restrict__ w, uint32_t* __restrict__ flag) {
    __shared__ int nonbin;
    if (threadIdx.x == 0) nonbin = 0;
    __syncthreads();
    int bad = 0;
    for (int i = threadIdx.x; i < 4096; i += 256) bad |= (w[i] > 1u) ? 1 : 0;
    if (bad) atomicOr(&nonbin, 1);
    __syncthreads();
    if (threadIdx.x == 0) *flag = (uint32_t)(nonbin != 0);
}

// K -> bf16, elementwise (8 elems/thread).
__global__ void convert_k_kernel(const float* __restrict__ src, ushort* __restrict__ dst) {
    const int i = blockIdx.x * 256 + threadIdx.x;
    f32x4 a = *(const f32x4*)(src + (size_t)i * 8);
    f32x4 b = *(const f32x4*)(src + (size_t)i * 8 + 4);
    *(bf16x8*)(dst + (size_t)i * 8) = pack8v(a, b);
}

// V -> transposed bf16 Vt[b][d][k] via LDS tile.
__global__ void convert_vt_kernel(const float* __restrict__ v, ushort* __restrict__ vt) {
    __shared__ alignas(16) float Lt[64][68];
    const int kt = blockIdx.x, b = blockIdx.y;
    const int tid = (int)threadIdx.x;
    const int r = tid >> 2, c4 = tid & 3;
    const float* vb = v + ((size_t)b * LL + kt * 64) * DD;
    #pragma unroll
    for (int j = 0; j < 4; ++j)
        *(f32x4*)&Lt[r][c4 * 16 + j * 4] = *(const f32x4*)(vb + (size_t)r * DD + c4 * 16 + j * 4);
    __syncthreads();
    ushort* vout = vt + (size_t)b * DD * LL + (size_t)r * LL + kt * 64 + c4 * 16;
    bf16x8 o0, o1;
    #pragma unroll
    for (int j = 0; j < 8; ++j) o0[j] = f2bfs(Lt[c4 * 16 + j][r]);
    #pragma unroll
    for (int j = 0; j < 8; ++j) o1[j] = f2bfs(Lt[c4 * 16 + 8 + j][r]);
    *(bf16x8*)vout = o0;
    *(bf16x8*)(vout + 8) = o1;
}

// Block = 64 q-rows of one batch, 512 threads / 8 waves (rg=w&3 q-group, ch=w>>2
// 32-k half). K and V^T tiles stream via global_load_lds (pre-swizzled global
// source, linear LDS dest); mask u64 via pinned inline-asm load one tile ahead;
// counted s_waitcnt vmcnt(N) -- never 0 in the loop. P stays in registers
// (permuted-K QK); pass 2 recomputes QK and writes normalized attn.
__global__ __launch_bounds__(512, 4) void fused_attn_kernel(
    const float* __restrict__ qg, const ushort* __restrict__ kbf,
    const ushort* __restrict__ vtb, const void* __restrict__ maskv,
    const uint32_t* __restrict__ flagp,
    float* __restrict__ attn, float* __restrict__ outp)
{
    __shared__ alignas(16) ushort KB[4][KT * 64];  // p1: K dbuf {0,1}, V^T dbuf {2,3}; p2: two 128-row K pairs
    __shared__ uint8_t Msk[8][NT][64];             // mask bits [wave][tile][lane] (32 KB)
    __shared__ float Rs[128];

    const int tid = (int)threadIdx.x;
    const int w   = tid >> 6, l = tid & 63;
    const int lr  = l & 15, lg = l >> 4;
    const int rg  = w & 3, ch = w >> 2;
    const int id  = (int)blockIdx.x;     // id = qt*8 + b
    const int b   = id & 7;
    const int q0  = (id >> 3) * 64;
    const bool mbyte = (*flagp != 0);

    const ushort* kb = kbf + (size_t)b * LL * DD;        // bf16 K [k][d]
    const ushort* vtg = vtb + (size_t)b * DD * LL;       // bf16 V^T [d][k]

    const int qrow = q0 + 16 * rg + lr;
    const uint8_t* mrow8  = (const uint8_t*)maskv + (size_t)b * LL * LL + (size_t)qrow * LL + ch * 32 + lg * 8;
    const int*     mrow32 = (const int*)maskv     + (size_t)b * LL * LL + (size_t)qrow * LL + ch * 32 + lg * 8;
    float* arow = attn + (size_t)b * LL * LL + (size_t)qrow * LL + ch * 32 + lg * 8;

    bf16x8 qf0, qf1;
    {
        const float* qp = qg + (size_t)(b * LL + qrow) * DD + lg * 8;
        qf0 = pack8v(*(const f32x4*)(qp)      * QSCALE, *(const f32x4*)(qp + 4)  * QSCALE);
        qf1 = pack8v(*(const f32x4*)(qp + 32) * QSCALE, *(const f32x4*)(qp + 36) * QSCALE);
    }

    // ---------- DMA staging: per wave 1KB of K, 1KB of V^T per tile ----------
    const int drow = w * 8 + (l >> 3);   // K row / V d-row staged by this lane
    const int dc   = l & 7;              // 16B chunk
    const int kchunk = dc ^ swzK(drow);  // pre-swizzled global chunk (K)
    const int vchunk = dc ^ swzV(drow);  // pre-swizzled global chunk (V^T)
    ushort* ldsK0 = &KB[0][0] + (tid >> 6) * 512;   // wave-uniform + lane*8 handled by HW
    // (gl_lds16 uses base + lane*16B internally; pass wave base only)
    auto dmaK = [&](int kt, int buf) {
        gl_lds16(kb + (size_t)(kt * KT + drow) * 64 + 8 * kchunk, &KB[buf][w * 512]);
    };
    auto dmaV = [&](int kt, int buf) {
        gl_lds16(vtg + (size_t)drow * LL + kt * KT + 8 * vchunk, &KB[2 + buf][w * 512]);
    };
    auto dmaK2 = [&](int kt2, int pair) {   // pass-2: 128 rows into buffer pair
        gl_lds16(kb + (size_t)(kt2 * 128 + drow) * 64 + 8 * kchunk, &KB[2 * pair][w * 512]);
        gl_lds16(kb + (size_t)(kt2 * 128 + 64 + drow) * 64 + 8 * kchunk, &KB[2 * pair + 1][w * 512]);
    };
    unsigned long long mA = 0, mB = 0;
    #define ASM_MLOAD(dst, kt) { unsigned long long a_ = (unsigned long long)(uintptr_t)(mrow8 + (kt) * KT); \
        asm volatile("global_load_dwordx2 %0, %1, off" : "=v"(dst) : "v"(a_) : "memory"); }

    // ================= pass 1: rowsums + unnormalized PV (P in regs) =================
    float rsum = 0.f;
    f32x4 oacc[4];
    #pragma unroll
    for (int g = 0; g < 4; ++g) { f32x4 z = {0.f, 0.f, 0.f, 0.f}; oacc[g] = z; }

    auto body1 = [&](int buf, unsigned long long mu, int kt) {
        int4 mi0 = {0,0,0,0}, mi1 = {0,0,0,0};
        if (!mbyte) { mi0 = *(const int4*)(mrow32 + kt * KT); mi1 = *(const int4*)(mrow32 + kt * KT + 4); }
        uint32_t mbits = 0;
        float p8[8];
        #pragma unroll
        for (int n = 0; n < 2; ++n) {
            const int krow = ch * 32 + ((lr >> 2) << 3) + (n << 2) + (lr & 3);
            bf16x8 k0 = *(const bf16x8*)&KB[buf][krow * 64 + ((lg       ^ swzK(krow)) << 3)];
            bf16x8 k1 = *(const bf16x8*)&KB[buf][krow * 64 + (((4 + lg) ^ swzK(krow)) << 3)];
            f32x4 c = {0.f, 0.f, 0.f, 0.f};
            c = __builtin_amdgcn_mfma_f32_16x16x32_bf16(k0, qf0, c, 0, 0, 0);
            c = __builtin_amdgcn_mfma_f32_16x16x32_bf16(k1, qf1, c, 0, 0, 0);
            #pragma unroll
            for (int j = 0; j < 4; ++j) {
                const int t = n * 4 + j;
                int mk;
                if (mbyte) mk = (int)((mu >> (8 * t)) & 0xffu);
                else {
                    const int4 mi = n ? mi1 : mi0;
                    mk = (j == 0) ? mi.x : (j == 1) ? mi.y : (j == 2) ? mi.z : mi.w;
                }
                mbits |= (mk ? 1u : 0u) << t;
                const float pv = mk ? 0.f : exp2f(c[j]);
                rsum += pv;
                p8[t] = pv;
            }
        }
        Msk[w][kt][l] = (uint8_t)mbits;
        bf16x8 pa;
        #pragma unroll
        for (int t = 0; t < 8; ++t) pa[t] = f2bfs(p8[t]);
        __builtin_amdgcn_s_setprio(1);
        #pragma unroll
        for (int g = 0; g < 4; ++g) {
            const int d = g * 16 + lr;
            bf16x8 vf = *(const bf16x8*)&KB[2 + buf][d * 64 + (((ch * 4 + lg) ^ swzV(d)) << 3)];
            oacc[g] = __builtin_amdgcn_mfma_f32_16x16x32_bf16(pa, vf, oacc[g], 0, 0, 0);
        }
        __builtin_amdgcn_s_setprio(0);
    };

    // prologue: tiles 0 and 1 in flight
    dmaK(0, 0); dmaV(0, 0); if (mbyte) ASM_MLOAD(mA, 0);
    dmaK(1, 1); dmaV(1, 1); if (mbyte) ASM_MLOAD(mB, 1);
    #pragma unroll 1
    for (int kt = 0; kt < NT; kt += 2) {
        // ---- even tile kt (buf0, mA) ----
        if (mbyte) asm volatile("s_waitcnt vmcnt(3)" ::: "memory");
        else       asm volatile("s_waitcnt vmcnt(2)" ::: "memory");
        __builtin_amdgcn_sched_barrier(0);
        wg_barrier();                       // tile kt staged for all waves
        body1(0, mA, kt);
        wg_barrier();                       // all waves done reading buf0
        if (kt + 2 < NT) { dmaK(kt + 2, 0); dmaV(kt + 2, 0); if (mbyte) ASM_MLOAD(mA, kt + 2); }
        // ---- odd tile kt+1 (buf1, mB) ----
        if (mbyte) asm volatile("s_waitcnt vmcnt(3)" ::: "memory");
        else       asm volatile("s_waitcnt vmcnt(2)" ::: "memory");
        __builtin_amdgcn_sched_barrier(0);
        wg_barrier();
        body1(1, mB, kt + 1);
        wg_barrier();
        if (kt + 3 < NT) { dmaK(kt + 3, 1); dmaV(kt + 3, 1); if (mbyte) ASM_MLOAD(mB, kt + 3); }
    }

    rsum += __shfl_xor(rsum, 16, 64);
    rsum += __shfl_xor(rsum, 32, 64);
    if (lg == 0) Rs[ch * 64 + 16 * rg + lr] = rsum;
    __syncthreads();
    const float rinv = 1.0f / (Rs[16 * rg + lr] + Rs[64 + 16 * rg + lr]);

    // epilogue: combine ch halves of O via retired KB region
    float* OutL = (float*)KB;
    if (ch == 1) {
        #pragma unroll
        for (int g = 0; g < 4; ++g)
            #pragma unroll
            for (int j = 0; j < 4; ++j)
                OutL[rg * 1088 + (lg * 4 + j) * 68 + g * 16 + lr] = oacc[g][j];
    }
    __syncthreads();
    if (ch == 0) {
        #pragma unroll
        for (int j = 0; j < 4; ++j) {
            const int ql = 16 * rg + lg * 4 + j;
            const float ri = 1.0f / (Rs[ql] + Rs[64 + ql]);
            const size_t orow = (size_t)(b * LL + q0 + ql) * DD;
            #pragma unroll
            for (int g = 0; g < 4; ++g)
                outp[orow + g * 16 + lr] = (oacc[g][j] + OutL[rg * 1088 + (lg * 4 + j) * 68 + g * 16 + lr]) * ri;
        }
    }
    __syncthreads();   // OutL reads complete BEFORE pass-2 DMA restages KB

    // ================= pass 2: recompute + attn write (128-wide tiles) =================
    auto body2 = [&](int pair, int idx) {
        const int kbase2 = idx * 128;
        #pragma unroll
        for (int h = 0; h < 2; ++h) {
            const int mb2 = (int)Msk[w][2 * idx + h][l];
            const ushort* Kbuf = KB[2 * pair + h];
            int4 mi0 = {0,0,0,0}, mi1 = {0,0,0,0};
            if (!mbyte) {
                mi0 = *(const int4*)(mrow32 + kbase2 + h * 64);
                mi1 = *(const int4*)(mrow32 + kbase2 + h * 64 + 4);
            }
            (void)mi0; (void)mi1;
            #pragma unroll
            for (int n = 0; n < 2; ++n) {
                const int krow = ch * 32 + ((lr >> 2) << 3) + (n << 2) + (lr & 3);
                bf16x8 k0 = *(const bf16x8*)&Kbuf[krow * 64 + ((lg       ^ swzK(krow)) << 3)];
                bf16x8 k1 = *(const bf16x8*)&Kbuf[krow * 64 + (((4 + lg) ^ swzK(krow)) << 3)];
                f32x4 c = {0.f, 0.f, 0.f, 0.f};
                c = __builtin_amdgcn_mfma_f32_16x16x32_bf16(k0, qf0, c, 0, 0, 0);
                c = __builtin_amdgcn_mfma_f32_16x16x32_bf16(k1, qf1, c, 0, 0, 0);
                f32x4 pv;
                #pragma unroll
                for (int j = 0; j < 4; ++j)
                    pv[j] = ((mb2 >> (n * 4 + j)) & 1) ? 0.f : exp2f(c[j]) * rinv;
                *(f32x4*)(arow + kbase2 + h * 64 + n * 4) = pv;
            }
        }
    };

    dmaK2(0, 0); dmaK2(1, 1);
    #pragma unroll 1
    for (int kt2 = 0; kt2 < NP2; ++kt2) {
        const int pair = kt2 & 1;
        asm volatile("s_waitcnt vmcnt(2)" ::: "memory");   // K2(kt2) landed; stores long retired
        __builtin_amdgcn_sched_barrier(0);
        wg_barrier();
        body2(pair, kt2);
        wg_barrier();
        if (kt2 + 2 < NP2) dmaK2(kt2 + 2, pair);
    }
}

extern "C" void kernel_launch(void* const* d_in, const int* in_sizes, int n_in,
                              void* d_out, int out_size, void* d_ws, size_t ws_size,
                              hipStream_t stream) {
    const float* q = (const float*)d_in[0];
    const float* k = (const float*)d_in[1];
    const float* v = (const float*)d_in[2];
    const void* mask = d_in[3];
    float* attn = (float*)d_out;
    float* outp = attn + (size_t)BB * LL * LL;
    uint32_t* flagp = (uint32_t*)d_ws;
    ushort* kbf = (ushort*)((char*)d_ws + 4096);                 // bf16 K   [b][k][d], 4 MB
    ushort* vtb = kbf + (size_t)BB * LL * DD;                    // bf16 V^T [b][d][k], 4 MB

    detect_mask_kernel<<<1, 256, 0, stream>>>((const uint32_t*)mask, flagp);
    convert_k_kernel<<<dim3(BB * LL * DD / 8 / 256), 256, 0, stream>>>(k, kbf);
    convert_vt_kernel<<<dim3(LL / 64, BB), 256, 0, stream>>>(v, vtb);
    fused_attn_kernel<<<dim3((LL / 64) * BB), 512, 0, stream>>>(q, kbf, vtb, mask, flagp, attn, outp);
}